// Round 5
// baseline (156.413 us; speedup 1.0000x reference)
//
#include <hip/hip_runtime.h>

typedef _Float16 f16;
typedef _Float16 f16x4 __attribute__((ext_vector_type(4)));
typedef _Float16 f16x8 __attribute__((ext_vector_type(8)));
typedef float    f32x4 __attribute__((ext_vector_type(4)));

#define S2C 2.88539008177792681472f   // 2*log2(e)

// ws layout, f16-element offsets
#define OFF_STF  0u          // states A-frags [10][256 rg2][2 rt][2 ks][64 lane][8]  5242880
#define OFF_AC   5242880u    // action f16 compact [8192][10][16]                     1310720
#define OFF_WEF  6553600u    // W_edge B-frags [90][4 ks][8 cg][64 lane][8]           1474560
#define OFF_WNF  8028160u    // W_node B-frags K-permuted [10][7 ks][4 c][64 lane][8]  143360
#define OFF_BE2  8171520u    // f32: be2[11520], bn2[640]; then 8 f16 zeros
#define OFF_Z    8195840u    // 8 f16 zeros (pad source for action kstep)

__device__ __forceinline__ float fast_exp2(float x){
#if __has_builtin(__builtin_amdgcn_exp2f)
    return __builtin_amdgcn_exp2f(x);
#else
    return exp2f(x);
#endif
}
__device__ __forceinline__ float fast_rcp(float x){
#if __has_builtin(__builtin_amdgcn_rcpf)
    return __builtin_amdgcn_rcpf(x);
#else
    return 1.0f/x;
#endif
}

#define MFMA16(a,b,c) __builtin_amdgcn_mfma_f32_16x16x32_f16(a,b,c,0,0,0)

// ---------------- prologue: cvt + fragment-order + bias scale ----------------
__global__ void prep(const float* __restrict__ st, const float* __restrict__ ac,
                     const float* __restrict__ We, const float* __restrict__ be,
                     const float* __restrict__ Wn, const float* __restrict__ bn,
                     f16* __restrict__ ws16){
    const int bid = blockIdx.x, t = threadIdx.x;
    if (bid < 2560){                                   // states -> A-fragment order
        int g = bid*256 + t;                           // [node][rg2][rt][ks][lane]
        int lane = g&63, ks = (g>>6)&1, rt = (g>>7)&1, rg2 = (g>>8)&255, node = g>>16;
        int row = rg2*32 + rt*16 + (lane&15);
        int k   = ks*32 + (lane>>4)*8;
        const float* src = st + ((size_t)row*10 + node)*64 + k;
        const float4 v0 = *(const float4*)src;
        const float4 v1 = *(const float4*)(src+4);
        f16x8 h; h[0]=(f16)v0.x; h[1]=(f16)v0.y; h[2]=(f16)v0.z; h[3]=(f16)v0.w;
                 h[4]=(f16)v1.x; h[5]=(f16)v1.y; h[6]=(f16)v1.z; h[7]=(f16)v1.w;
        *(f16x8*)(ws16 + OFF_STF + (size_t)g*8) = h;
    } else if (bid < 3840){                            // action f32 -> f16 compact
        int g = (bid-2560)*256 + t;                    // 327680 float4s
        const float4 v = ((const float4*)ac)[g];
        f16x4 h; h[0]=(f16)v.x; h[1]=(f16)v.y; h[2]=(f16)v.z; h[3]=(f16)v.w;
        *(f16x4*)(ws16 + OFF_AC + (size_t)g*4) = h;
    } else if (bid < 4560){                            // W_edge -> B-fragment order
        int g = (bid-3840)*256 + t;                    // < 184320
        int l = g & 15, q = (g>>4)&3, cg = (g>>6)&7, ks = (g>>9)&3, e = g>>11;
        const float* src = We + e*16384 + (ks*32 + q*8)*128 + cg*16 + l;
        f16x8 h;
        #pragma unroll
        for (int u=0;u<8;u++) h[u] = (f16)src[u*128];
        *(f16x8*)(ws16 + OFF_WEF + (size_t)g*8) = h;
    } else if (bid < 4630){                            // W_node -> B-frags, K-permuted
        int g = (bid-4560)*256 + t;                    // < 17920
        if (g < 17920){
            int l = g&15, q=(g>>4)&3, c=(g>>6)&3, r=g>>8;
            int ks2 = r % 7, kn = r / 7;
            f16x8 h;
            #pragma unroll
            for (int u=0;u<8;u++){
                int knew = ks2*32 + q*8 + u;
                // K-order: [agg 0..127 -> f=knew+80][states 128..191 & action 192..207 -> f=knew-128][pad]
                int f = (knew < 128) ? (knew + 80) : (knew - 128);
                h[u] = (knew < 208) ? (f16)Wn[kn*13312 + f*64 + c*16 + l] : (f16)0.0f;
            }
            *(f16x8*)(ws16 + OFF_WNF + (size_t)kn*14336 + ((size_t)(ks2*4+c)*64 + q*16 + l)*8) = h;
        }
    } else {                                           // biases * 2log2e, zero pad
        int g = (bid-4630)*256 + t;
        float* be2 = (float*)(ws16 + OFF_BE2);
        if (g < 11520)      be2[g] = S2C*be[g];
        else if (g < 12160) be2[g] = S2C*bn[g-11520];
        else if (g < 12168) ws16[OFF_Z + (g-12160)] = (f16)0.0f;
    }
}

// ---------------- main kernel: barrier-free stage 1, one barrier total ----------------
// block = 64 batch rows x node i; wave = 32 rows x 64 H-cols (stage 1), 16 rows x 64 d (stage 2)
__launch_bounds__(256, 3)
__global__ void gnn_main(const f16* __restrict__ ws16, float* __restrict__ out){
    __shared__ alignas(16) f16 sAgg[64*128];           // 16 KB

    const f16* stf = ws16 + OFF_STF;
    const f16* Wef = ws16 + OFF_WEF;
    const float* be2 = (const float*)(ws16 + OFF_BE2);
    const float* bn2 = be2 + 11520;

    const int t = threadIdx.x, lane = t&63, wid = t>>6;
    const int l15 = lane&15, q = lane>>4, qo = q<<3;
    const int i  = blockIdx.x >> 7;
    const int rb = blockIdx.x & 127;
    const int b0 = rb*64;
    const int rg2 = rb*2 + (wid>>1);                   // global 32-row group
    const int cs  = wid&1;                             // H column half

    // states_i A-frags, register-resident across all 9 edges
    f16x8 ai[4];
    {
        const f16* p = stf + (size_t)(i*256 + rg2)*2048 + lane*8;
        ai[0] = *(const f16x8*)p;        ai[1] = *(const f16x8*)(p+512);
        ai[2] = *(const f16x8*)(p+1024); ai[3] = *(const f16x8*)(p+1536);
    }

    f32x4 agg[2][4] = {};

    #pragma unroll 1
    for (int e=0; e<9; ++e){
        const int j = e + (e >= i);
        const int ebase = 9*i + e;

        f16x8 aj[4];
        {
            const f16* p = stf + (size_t)(j*256 + rg2)*2048 + lane*8;
            aj[0] = *(const f16x8*)p;        aj[1] = *(const f16x8*)(p+512);
            aj[2] = *(const f16x8*)(p+1024); aj[3] = *(const f16x8*)(p+1536);
        }
        float bv[4];
        #pragma unroll
        for (int c=0; c<4; ++c) bv[c] = be2[ebase*128 + cs*64 + c*16 + l15];

        f32x4 msg[2][4] = {};
        #pragma unroll
        for (int ks4=0; ks4<4; ++ks4){
            const f16* wb = Wef + (size_t)((ebase*4 + ks4)*8 + cs*4)*512 + lane*8;
            f16x8 bf[4];
            #pragma unroll
            for (int c=0; c<4; ++c) bf[c] = *(const f16x8*)(wb + c*512);
            #pragma unroll
            for (int rt=0; rt<2; ++rt){
                f16x8 a = (ks4 < 2) ? ai[rt*2 + ks4] : aj[rt*2 + (ks4-2)];
                #pragma unroll
                for (int c=0; c<4; ++c)
                    msg[rt][c] = MFMA16(a, bf[c], msg[rt][c]);
            }
        }
        // tanh + aggregate:  sum tanh = 9 - 2*sum rcp(exp2(S2C*x + b2)+1); +9 folded later
        #pragma unroll
        for (int rt=0; rt<2; ++rt)
            #pragma unroll
            for (int c=0; c<4; ++c)
                #pragma unroll
                for (int r2=0; r2<4; ++r2){
                    float tt = __builtin_fmaf(msg[rt][c][r2], S2C, bv[c]);
                    float rr = fast_rcp(fast_exp2(tt) + 1.0f);
                    agg[rt][c][r2] = __builtin_fmaf(-2.0f, rr, agg[rt][c][r2]);
                }
    }

    // ---- agg (C-layout) -> sAgg f16 (A-layout, swizzled), +9 fold; ONE barrier ----
    #pragma unroll
    for (int rt=0; rt<2; ++rt)
        #pragma unroll
        for (int c=0; c<4; ++c)
            #pragma unroll
            for (int r2=0; r2<4; ++r2){
                int lrow = (wid>>1)*32 + rt*16 + q*4 + r2;
                int col  = cs*64 + c*16 + l15;
                sAgg[lrow*128 + (((col>>3) ^ (lrow&7))<<3) + (col&7)] = (f16)(agg[rt][c][r2] + 9.0f);
            }
    __syncthreads();

    // ---- stage 2: out = tanh([agg|states|action] @ Wn_perm[i] + bn) ; wave = 16 rows ----
    f32x4 acc[4] = {};
    const f16* wnb = ws16 + OFF_WNF + (size_t)i*14336;
    const f16* acp = ws16 + OFF_AC;
    const f16* zb  = ws16 + OFF_Z;
    #pragma unroll
    for (int ks2=0; ks2<7; ++ks2){
        f16x8 a;
        if (ks2 < 4){                                  // agg region (K 0..127)
            int lrow = wid*16 + l15;
            a = *(const f16x8*)(sAgg + lrow*128 + (((ks2*4 + q) ^ (l15&7))<<3));
        } else if (ks2 < 6){                           // states region (K 128..191)
            int fi = ((i*256 + rb*2 + (wid>>1))*2 + (wid&1))*2 + (ks2-4);
            a = *(const f16x8*)(stf + (size_t)fi*512 + lane*8);
        } else {                                       // action (K 192..207) + zero pad
            int row = b0 + wid*16 + l15;
            const f16* ap = (q < 2) ? (acp + ((size_t)row*10 + i)*16 + qo) : zb;
            a = *(const f16x8*)ap;
        }
        f16x8 bf[4];
        #pragma unroll
        for (int c=0; c<4; ++c)
            bf[c] = *(const f16x8*)(wnb + (size_t)(ks2*4+c)*512 + lane*8);
        #pragma unroll
        for (int c=0; c<4; ++c)
            acc[c] = MFMA16(a, bf[c], acc[c]);
    }
    float bnv[4];
    #pragma unroll
    for (int c=0; c<4; ++c) bnv[c] = bn2[i*64 + c*16 + l15];
    #pragma unroll
    for (int c=0; c<4; ++c)
        #pragma unroll
        for (int r2=0; r2<4; ++r2){
            int row = b0 + wid*16 + q*4 + r2;
            int col = c*16 + l15;
            float tt = __builtin_fmaf(acc[c][r2], S2C, bnv[c]);
            float rr = fast_rcp(fast_exp2(tt) + 1.0f);
            out[((size_t)row*10 + i)*64 + col] = __builtin_fmaf(-2.0f, rr, 1.0f);
        }
}

extern "C" void kernel_launch(void* const* d_in, const int* in_sizes, int n_in,
                              void* d_out, int out_size, void* d_ws, size_t ws_size,
                              hipStream_t stream) {
    const float* states = (const float*)d_in[0];
    const float* action = (const float*)d_in[1];
    const float* W_edge = (const float*)d_in[2];
    const float* b_edge = (const float*)d_in[3];
    const float* W_node = (const float*)d_in[4];
    const float* b_node = (const float*)d_in[5];
    f16* ws16 = (f16*)d_ws;   // ~16.4 MB used

    hipLaunchKernelGGL(prep, dim3(4678), dim3(256), 0, stream,
                       states, action, W_edge, b_edge, W_node, b_node, ws16);
    hipLaunchKernelGGL(gnn_main, dim3(1280), dim3(256), 0, stream,
                       ws16, (float*)d_out);
}

// Round 6
// 143.384 us; speedup vs baseline: 1.0909x; 1.0909x over previous
//
#include <hip/hip_runtime.h>

typedef _Float16 f16;
typedef _Float16 f16x4 __attribute__((ext_vector_type(4)));
typedef _Float16 f16x8 __attribute__((ext_vector_type(8)));
typedef float    f32x4 __attribute__((ext_vector_type(4)));

#define S2C 2.88539008177792681472f   // 2*log2(e)

// ws layout, f16-element offsets
#define OFF_STF  0u          // states A-frags [10][256 rg2][2 rt][2 ks][64 lane][8]  5242880
#define OFF_AC   5242880u    // action f16 compact [8192][10][16]                     1310720
#define OFF_WEF  6553600u    // W_edge B-frags [90][4 ks][8 cg][64 lane][8]           1474560
#define OFF_WNF  8028160u    // W_node B-frags K-permuted [10][7 ks][4 c][64 lane][8]  143360
#define OFF_BE2  8171520u    // f32: be2[11520], bn2[640]; then 8 f16 zeros
#define OFF_Z    8195840u    // 8 f16 zeros (pad source for action kstep)

__device__ __forceinline__ float fast_exp2(float x){
#if __has_builtin(__builtin_amdgcn_exp2f)
    return __builtin_amdgcn_exp2f(x);
#else
    return exp2f(x);
#endif
}
__device__ __forceinline__ float fast_rcp(float x){
#if __has_builtin(__builtin_amdgcn_rcpf)
    return __builtin_amdgcn_rcpf(x);
#else
    return 1.0f/x;
#endif
}

#define MFMA16(a,b,c) __builtin_amdgcn_mfma_f32_16x16x32_f16(a,b,c,0,0,0)

// ---------------- prologue: cvt + fragment-order + bias scale (unchanged) ----------------
__global__ void prep(const float* __restrict__ st, const float* __restrict__ ac,
                     const float* __restrict__ We, const float* __restrict__ be,
                     const float* __restrict__ Wn, const float* __restrict__ bn,
                     f16* __restrict__ ws16){
    const int bid = blockIdx.x, t = threadIdx.x;
    if (bid < 2560){                                   // states -> A-fragment order
        int g = bid*256 + t;                           // [node][rg2][rt][ks][lane]
        int lane = g&63, ks = (g>>6)&1, rt = (g>>7)&1, rg2 = (g>>8)&255, node = g>>16;
        int row = rg2*32 + rt*16 + (lane&15);
        int k   = ks*32 + (lane>>4)*8;
        const float* src = st + ((size_t)row*10 + node)*64 + k;
        const float4 v0 = *(const float4*)src;
        const float4 v1 = *(const float4*)(src+4);
        f16x8 h; h[0]=(f16)v0.x; h[1]=(f16)v0.y; h[2]=(f16)v0.z; h[3]=(f16)v0.w;
                 h[4]=(f16)v1.x; h[5]=(f16)v1.y; h[6]=(f16)v1.z; h[7]=(f16)v1.w;
        *(f16x8*)(ws16 + OFF_STF + (size_t)g*8) = h;
    } else if (bid < 3840){                            // action f32 -> f16 compact
        int g = (bid-2560)*256 + t;                    // 327680 float4s
        const float4 v = ((const float4*)ac)[g];
        f16x4 h; h[0]=(f16)v.x; h[1]=(f16)v.y; h[2]=(f16)v.z; h[3]=(f16)v.w;
        *(f16x4*)(ws16 + OFF_AC + (size_t)g*4) = h;
    } else if (bid < 4560){                            // W_edge -> B-fragment order
        int g = (bid-3840)*256 + t;                    // < 184320
        int l = g & 15, q = (g>>4)&3, cg = (g>>6)&7, ks = (g>>9)&3, e = g>>11;
        const float* src = We + e*16384 + (ks*32 + q*8)*128 + cg*16 + l;
        f16x8 h;
        #pragma unroll
        for (int u=0;u<8;u++) h[u] = (f16)src[u*128];
        *(f16x8*)(ws16 + OFF_WEF + (size_t)g*8) = h;
    } else if (bid < 4630){                            // W_node -> B-frags, K-permuted
        int g = (bid-4560)*256 + t;                    // < 17920
        if (g < 17920){
            int l = g&15, q=(g>>4)&3, c=(g>>6)&3, r=g>>8;
            int ks2 = r % 7, kn = r / 7;
            f16x8 h;
            #pragma unroll
            for (int u=0;u<8;u++){
                int knew = ks2*32 + q*8 + u;
                // K-order: [agg 0..127 -> f=knew+80][states/action 128..207 -> f=knew-128][pad]
                int f = (knew < 128) ? (knew + 80) : (knew - 128);
                h[u] = (knew < 208) ? (f16)Wn[kn*13312 + f*64 + c*16 + l] : (f16)0.0f;
            }
            *(f16x8*)(ws16 + OFF_WNF + (size_t)kn*14336 + ((size_t)(ks2*4+c)*64 + q*16 + l)*8) = h;
        }
    } else {                                           // biases * 2log2e, zero pad
        int g = (bid-4630)*256 + t;
        float* be2 = (float*)(ws16 + OFF_BE2);
        if (g < 11520)      be2[g] = S2C*be[g];
        else if (g < 12160) be2[g] = S2C*bn[g-11520];
        else if (g < 12168) ws16[OFF_Z + (g-12160)] = (f16)0.0f;
    }
}

// ---------------- main kernel: 128-thread blocks (2 waves, 32 rows), 2560 blocks ----------------
// wave = 32 rows x 64 H-cols (stage 1), 16 rows x 64 d (stage 2); one barrier total
__launch_bounds__(128, 4)
__global__ void gnn_main(const f16* __restrict__ ws16, float* __restrict__ out){
    __shared__ alignas(16) f16 sAgg[32*128];           // 8 KB

    const f16* stf = ws16 + OFF_STF;
    const f16* Wef = ws16 + OFF_WEF;
    const float* be2 = (const float*)(ws16 + OFF_BE2);
    const float* bn2 = be2 + 11520;

    const int t = threadIdx.x, lane = t&63, wid = t>>6;   // wid in {0,1}
    const int l15 = lane&15, q = lane>>4, qo = q<<3;
    const int i  = blockIdx.x >> 8;                    // node 0..9
    const int rb = blockIdx.x & 255;                   // 32-row group 0..255
    const int b0 = rb*32;
    const int cs = wid;                                // H column half

    // states_i A-frags, register-resident across all 9 edges
    f16x8 ai[4];
    {
        const f16* p = stf + (size_t)(i*256 + rb)*2048 + lane*8;
        ai[0] = *(const f16x8*)p;        ai[1] = *(const f16x8*)(p+512);
        ai[2] = *(const f16x8*)(p+1024); ai[3] = *(const f16x8*)(p+1536);
    }

    f32x4 agg[2][4] = {};

    #pragma unroll 1
    for (int e=0; e<9; ++e){
        const int j = e + (e >= i);
        const int ebase = 9*i + e;

        f16x8 aj[4];
        {
            const f16* p = stf + (size_t)(j*256 + rb)*2048 + lane*8;
            aj[0] = *(const f16x8*)p;        aj[1] = *(const f16x8*)(p+512);
            aj[2] = *(const f16x8*)(p+1024); aj[3] = *(const f16x8*)(p+1536);
        }
        float bv[4];
        #pragma unroll
        for (int c=0; c<4; ++c) bv[c] = be2[ebase*128 + cs*64 + c*16 + l15];

        f32x4 msg[2][4] = {};
        #pragma unroll
        for (int ks4=0; ks4<4; ++ks4){
            const f16* wb = Wef + (size_t)((ebase*4 + ks4)*8 + cs*4)*512 + lane*8;
            f16x8 bf[4];
            #pragma unroll
            for (int c=0; c<4; ++c) bf[c] = *(const f16x8*)(wb + c*512);
            #pragma unroll
            for (int rt=0; rt<2; ++rt){
                f16x8 a = (ks4 < 2) ? ai[rt*2 + ks4] : aj[rt*2 + (ks4-2)];
                #pragma unroll
                for (int c=0; c<4; ++c)
                    msg[rt][c] = MFMA16(a, bf[c], msg[rt][c]);
            }
        }
        // tanh + aggregate:  sum tanh = 9 - 2*sum rcp(exp2(S2C*x + b2)+1); +9 folded later
        #pragma unroll
        for (int rt=0; rt<2; ++rt)
            #pragma unroll
            for (int c=0; c<4; ++c)
                #pragma unroll
                for (int r2=0; r2<4; ++r2){
                    float tt = __builtin_fmaf(msg[rt][c][r2], S2C, bv[c]);
                    float rr = fast_rcp(fast_exp2(tt) + 1.0f);
                    agg[rt][c][r2] = __builtin_fmaf(-2.0f, rr, agg[rt][c][r2]);
                }
    }

    // ---- agg (C-layout) -> sAgg f16 (A-layout, swizzled), +9 fold; ONE barrier ----
    #pragma unroll
    for (int rt=0; rt<2; ++rt)
        #pragma unroll
        for (int c=0; c<4; ++c)
            #pragma unroll
            for (int r2=0; r2<4; ++r2){
                int lrow = rt*16 + q*4 + r2;           // 0..31
                int col  = cs*64 + c*16 + l15;         // 0..127
                sAgg[lrow*128 + (((col>>3) ^ (lrow&7))<<3) + (col&7)] = (f16)(agg[rt][c][r2] + 9.0f);
            }
    __syncthreads();

    // ---- stage 2: out = tanh([agg|states|action] @ Wn_perm[i] + bn) ; wave = 16 rows ----
    f32x4 acc[4] = {};
    const f16* wnb = ws16 + OFF_WNF + (size_t)i*14336;
    const f16* acp = ws16 + OFF_AC;
    const f16* zb  = ws16 + OFF_Z;
    #pragma unroll
    for (int ks2=0; ks2<7; ++ks2){
        f16x8 a;
        if (ks2 < 4){                                  // agg region (K 0..127)
            int lrow = wid*16 + l15;
            a = *(const f16x8*)(sAgg + lrow*128 + (((ks2*4 + q) ^ (l15&7))<<3));
        } else if (ks2 < 6){                           // states region (K 128..191)
            a = *(const f16x8*)(stf + (size_t)(i*256 + rb)*2048 + wid*1024 + (ks2-4)*512 + lane*8);
        } else {                                       // action (K 192..207) + zero pad
            int row = b0 + wid*16 + l15;
            const f16* ap = (q < 2) ? (acp + ((size_t)row*10 + i)*16 + qo) : zb;
            a = *(const f16x8*)ap;
        }
        f16x8 bf[4];
        #pragma unroll
        for (int c=0; c<4; ++c)
            bf[c] = *(const f16x8*)(wnb + (size_t)(ks2*4+c)*512 + lane*8);
        #pragma unroll
        for (int c=0; c<4; ++c)
            acc[c] = MFMA16(a, bf[c], acc[c]);
    }
    float bnv[4];
    #pragma unroll
    for (int c=0; c<4; ++c) bnv[c] = bn2[i*64 + c*16 + l15];
    #pragma unroll
    for (int c=0; c<4; ++c)
        #pragma unroll
        for (int r2=0; r2<4; ++r2){
            int row = b0 + wid*16 + q*4 + r2;
            int col = c*16 + l15;
            float tt = __builtin_fmaf(acc[c][r2], S2C, bnv[c]);
            float rr = fast_rcp(fast_exp2(tt) + 1.0f);
            out[((size_t)row*10 + i)*64 + col] = __builtin_fmaf(-2.0f, rr, 1.0f);
        }
}

extern "C" void kernel_launch(void* const* d_in, const int* in_sizes, int n_in,
                              void* d_out, int out_size, void* d_ws, size_t ws_size,
                              hipStream_t stream) {
    const float* states = (const float*)d_in[0];
    const float* action = (const float*)d_in[1];
    const float* W_edge = (const float*)d_in[2];
    const float* b_edge = (const float*)d_in[3];
    const float* W_node = (const float*)d_in[4];
    const float* b_node = (const float*)d_in[5];
    f16* ws16 = (f16*)d_ws;   // ~16.4 MB used

    hipLaunchKernelGGL(prep, dim3(4678), dim3(256), 0, stream,
                       states, action, W_edge, b_edge, W_node, b_node, ws16);
    hipLaunchKernelGGL(gnn_main, dim3(2560), dim3(128), 0, stream,
                       ws16, (float*)d_out);
}

// Round 7
// 141.454 us; speedup vs baseline: 1.1057x; 1.0136x over previous
//
#include <hip/hip_runtime.h>

typedef _Float16 f16;
typedef _Float16 f16x4 __attribute__((ext_vector_type(4)));
typedef _Float16 f16x8 __attribute__((ext_vector_type(8)));
typedef float    f32x4 __attribute__((ext_vector_type(4)));

#define S2C 2.88539008177792681472f   // 2*log2(e)

// ws layout, f16-element offsets
#define OFF_STF  0u          // states A-frags [10][256 rg2][2 rt][2 ks][64 lane][8]  5242880
#define OFF_AC   5242880u    // action f16 compact [8192][10][16]                     1310720
#define OFF_WEF  6553600u    // W_edge B-frags [90][4 ks][8 cg][64 lane][8]           1474560
#define OFF_WNF  8028160u    // W_node B-frags K-permuted [10][7 ks][4 c][64 lane][8]  143360
#define OFF_BE2  8171520u    // f32: be2[11520], bn2[640]; then 8 f16 zeros
#define OFF_Z    8195840u    // 8 f16 zeros (pad source for action kstep)

__device__ __forceinline__ float fast_exp2(float x){
#if __has_builtin(__builtin_amdgcn_exp2f)
    return __builtin_amdgcn_exp2f(x);
#else
    return exp2f(x);
#endif
}
__device__ __forceinline__ float fast_rcp(float x){
#if __has_builtin(__builtin_amdgcn_rcpf)
    return __builtin_amdgcn_rcpf(x);
#else
    return 1.0f/x;
#endif
}

__device__ __forceinline__ void gl_lds16(const f16* g, f16* l){
    __builtin_amdgcn_global_load_lds(
        (const __attribute__((address_space(1))) unsigned int*)g,
        (__attribute__((address_space(3))) unsigned int*)l, 16, 0, 0);
}

#define MFMA16(a,b,c) __builtin_amdgcn_mfma_f32_16x16x32_f16(a,b,c,0,0,0)

// ---------------- prologue: cvt + fragment-order + bias scale (unchanged) ----------------
__global__ void prep(const float* __restrict__ st, const float* __restrict__ ac,
                     const float* __restrict__ We, const float* __restrict__ be,
                     const float* __restrict__ Wn, const float* __restrict__ bn,
                     f16* __restrict__ ws16){
    const int bid = blockIdx.x, t = threadIdx.x;
    if (bid < 2560){                                   // states -> A-fragment order
        int g = bid*256 + t;                           // [node][rg2][rt][ks][lane]
        int lane = g&63, ks = (g>>6)&1, rt = (g>>7)&1, rg2 = (g>>8)&255, node = g>>16;
        int row = rg2*32 + rt*16 + (lane&15);
        int k   = ks*32 + (lane>>4)*8;
        const float* src = st + ((size_t)row*10 + node)*64 + k;
        const float4 v0 = *(const float4*)src;
        const float4 v1 = *(const float4*)(src+4);
        f16x8 h; h[0]=(f16)v0.x; h[1]=(f16)v0.y; h[2]=(f16)v0.z; h[3]=(f16)v0.w;
                 h[4]=(f16)v1.x; h[5]=(f16)v1.y; h[6]=(f16)v1.z; h[7]=(f16)v1.w;
        *(f16x8*)(ws16 + OFF_STF + (size_t)g*8) = h;
    } else if (bid < 3840){                            // action f32 -> f16 compact
        int g = (bid-2560)*256 + t;                    // 327680 float4s
        const float4 v = ((const float4*)ac)[g];
        f16x4 h; h[0]=(f16)v.x; h[1]=(f16)v.y; h[2]=(f16)v.z; h[3]=(f16)v.w;
        *(f16x4*)(ws16 + OFF_AC + (size_t)g*4) = h;
    } else if (bid < 4560){                            // W_edge -> B-fragment order
        int g = (bid-3840)*256 + t;                    // < 184320
        int l = g & 15, q = (g>>4)&3, cg = (g>>6)&7, ks = (g>>9)&3, e = g>>11;
        const float* src = We + e*16384 + (ks*32 + q*8)*128 + cg*16 + l;
        f16x8 h;
        #pragma unroll
        for (int u=0;u<8;u++) h[u] = (f16)src[u*128];
        *(f16x8*)(ws16 + OFF_WEF + (size_t)g*8) = h;
    } else if (bid < 4630){                            // W_node -> B-frags, K-permuted
        int g = (bid-4560)*256 + t;                    // < 17920
        if (g < 17920){
            int l = g&15, q=(g>>4)&3, c=(g>>6)&3, r=g>>8;
            int ks2 = r % 7, kn = r / 7;
            f16x8 h;
            #pragma unroll
            for (int u=0;u<8;u++){
                int knew = ks2*32 + q*8 + u;
                // K-order: [agg 0..127 -> f=knew+80][states/action 128..207 -> f=knew-128][pad]
                int f = (knew < 128) ? (knew + 80) : (knew - 128);
                h[u] = (knew < 208) ? (f16)Wn[kn*13312 + f*64 + c*16 + l] : (f16)0.0f;
            }
            *(f16x8*)(ws16 + OFF_WNF + (size_t)kn*14336 + ((size_t)(ks2*4+c)*64 + q*16 + l)*8) = h;
        }
    } else {                                           // biases * 2log2e, zero pad
        int g = (bid-4630)*256 + t;
        float* be2 = (float*)(ws16 + OFF_BE2);
        if (g < 11520)      be2[g] = S2C*be[g];
        else if (g < 12160) be2[g] = S2C*bn[g-11520];
        else if (g < 12168) ws16[OFF_Z + (g-12160)] = (f16)0.0f;
    }
}

// ---------------- main kernel: BM=128, 512 threads (8 waves = 4 rg x 2 cs), 640 blocks ----
// W_edge staged once per block/edge into double-buffered LDS, prefetched one edge ahead.
__launch_bounds__(512, 4)
__global__ void gnn_main(const f16* __restrict__ ws16, float* __restrict__ out){
    __shared__ alignas(16) f16 S[32768];               // 64 KB: W buf0 @0, W buf1 @16384
                                                       // stage2: sAgg[128][128] overlays @0

    const f16* stf = ws16 + OFF_STF;
    const f16* Wef = ws16 + OFF_WEF;
    const float* be2 = (const float*)(ws16 + OFF_BE2);
    const float* bn2 = be2 + 11520;

    const int t = threadIdx.x, lane = t&63, wid = t>>6;   // wid 0..7
    const int l15 = lane&15, q = lane>>4, qo = q<<3;
    const int rg = wid>>1, cs = wid&1;                 // rowgroup 0..3, col half 0..1
    const int i  = blockIdx.x >> 6;                    // node 0..9
    const int rb = blockIdx.x & 63;                    // 128-row group
    const int b0 = rb*128;
    const int rg2 = rb*4 + rg;                         // global 32-row group

    // prologue: stage W(edge 9i) into buf0; load register-resident states_i frags
    const int e0 = 9*i;
    {
        const f16* wsrc = Wef + (size_t)e0*16384;
        #pragma unroll
        for (int it=0; it<4; ++it)
            gl_lds16(wsrc + (wid*4+it)*512 + lane*8, S + (wid*4+it)*512);
    }
    f16x8 ai[4];
    {
        const f16* p = stf + (size_t)(i*256 + rg2)*2048 + lane*8;
        ai[0] = *(const f16x8*)p;        ai[1] = *(const f16x8*)(p+512);
        ai[2] = *(const f16x8*)(p+1024); ai[3] = *(const f16x8*)(p+1536);
    }
    f32x4 agg[2][4] = {};
    __syncthreads();                                   // vmcnt drain -> buf0 ready

    #pragma unroll 1
    for (int e=0; e<9; ++e){
        const int ebase = e0 + e;
        const int j = e + (e >= i);

        if (e < 8){                                    // prefetch W(e+1) into alternate buffer
            const f16* wsrc = Wef + (size_t)(ebase+1)*16384;
            f16* wdst = S + (((e+1)&1)<<14);
            #pragma unroll
            for (int it=0; it<4; ++it)
                gl_lds16(wsrc + (wid*4+it)*512 + lane*8, wdst + (wid*4+it)*512);
        }
        f16x8 aj[4];
        {
            const f16* p = stf + (size_t)(j*256 + rg2)*2048 + lane*8;
            aj[0] = *(const f16x8*)p;        aj[1] = *(const f16x8*)(p+512);
            aj[2] = *(const f16x8*)(p+1024); aj[3] = *(const f16x8*)(p+1536);
        }
        float bv[4];
        #pragma unroll
        for (int c=0; c<4; ++c) bv[c] = be2[ebase*128 + cs*64 + c*16 + l15];

        const f16* wb = S + ((e&1)<<14) + (size_t)(cs*4)*512 + lane*8;
        f32x4 msg[2][4] = {};
        #pragma unroll
        for (int ks4=0; ks4<4; ++ks4){
            f16x8 bf[4];
            #pragma unroll
            for (int c=0; c<4; ++c) bf[c] = *(const f16x8*)(wb + (ks4*8 + c)*512);
            #pragma unroll
            for (int rt=0; rt<2; ++rt){
                f16x8 a = (ks4 < 2) ? ai[rt*2 + ks4] : aj[rt*2 + (ks4-2)];
                #pragma unroll
                for (int c=0; c<4; ++c)
                    msg[rt][c] = MFMA16(a, bf[c], msg[rt][c]);
            }
        }
        // tanh + aggregate:  sum tanh = 9 - 2*sum rcp(exp2(S2C*x + b2)+1); +9 folded later
        #pragma unroll
        for (int rt=0; rt<2; ++rt)
            #pragma unroll
            for (int c=0; c<4; ++c)
                #pragma unroll
                for (int r2=0; r2<4; ++r2){
                    float tt = __builtin_fmaf(msg[rt][c][r2], S2C, bv[c]);
                    float rr = fast_rcp(fast_exp2(tt) + 1.0f);
                    agg[rt][c][r2] = __builtin_fmaf(-2.0f, rr, agg[rt][c][r2]);
                }
        __syncthreads();                               // readers done before buffer reuse
    }

    // ---- agg (C-layout) -> sAgg f16 (A-layout, swizzled) overlaying W buffers ----
    #pragma unroll
    for (int rt=0; rt<2; ++rt)
        #pragma unroll
        for (int c=0; c<4; ++c)
            #pragma unroll
            for (int r2=0; r2<4; ++r2){
                int lrow = rg*32 + rt*16 + q*4 + r2;   // 0..127
                int col  = cs*64 + c*16 + l15;         // 0..127
                S[lrow*128 + (((col>>3) ^ (lrow&7))<<3) + (col&7)] = (f16)(agg[rt][c][r2] + 9.0f);
            }
    __syncthreads();

    // ---- stage 2: out = tanh([agg|states|action] @ Wn_perm[i] + bn) ; wave = 16 rows ----
    f32x4 acc[4] = {};
    const f16* wnb = ws16 + OFF_WNF + (size_t)i*14336;
    const f16* acp = ws16 + OFF_AC;
    const f16* zb  = ws16 + OFF_Z;
    #pragma unroll
    for (int ks2=0; ks2<7; ++ks2){
        f16x8 a;
        if (ks2 < 4){                                  // agg region (K 0..127)
            int lrow = wid*16 + l15;
            a = *(const f16x8*)(S + lrow*128 + (((ks2*4 + q) ^ (l15&7))<<3));
        } else if (ks2 < 6){                           // states region (K 128..191)
            int fi = ((i*256 + rb*4 + (wid>>1))*2 + (wid&1))*2 + (ks2-4);
            a = *(const f16x8*)(stf + (size_t)fi*512 + lane*8);
        } else {                                       // action (K 192..207) + zero pad
            int row = b0 + wid*16 + l15;
            const f16* ap = (q < 2) ? (acp + ((size_t)row*10 + i)*16 + qo) : zb;
            a = *(const f16x8*)ap;
        }
        f16x8 bf[4];
        #pragma unroll
        for (int c=0; c<4; ++c)
            bf[c] = *(const f16x8*)(wnb + (size_t)(ks2*4+c)*512 + lane*8);
        #pragma unroll
        for (int c=0; c<4; ++c)
            acc[c] = MFMA16(a, bf[c], acc[c]);
    }
    float bnv[4];
    #pragma unroll
    for (int c=0; c<4; ++c) bnv[c] = bn2[i*64 + c*16 + l15];
    #pragma unroll
    for (int c=0; c<4; ++c)
        #pragma unroll
        for (int r2=0; r2<4; ++r2){
            int row = b0 + wid*16 + q*4 + r2;
            int col = c*16 + l15;
            float tt = __builtin_fmaf(acc[c][r2], S2C, bnv[c]);
            float rr = fast_rcp(fast_exp2(tt) + 1.0f);
            out[((size_t)row*10 + i)*64 + col] = __builtin_fmaf(-2.0f, rr, 1.0f);
        }
}

extern "C" void kernel_launch(void* const* d_in, const int* in_sizes, int n_in,
                              void* d_out, int out_size, void* d_ws, size_t ws_size,
                              hipStream_t stream) {
    const float* states = (const float*)d_in[0];
    const float* action = (const float*)d_in[1];
    const float* W_edge = (const float*)d_in[2];
    const float* b_edge = (const float*)d_in[3];
    const float* W_node = (const float*)d_in[4];
    const float* b_node = (const float*)d_in[5];
    f16* ws16 = (f16*)d_ws;   // ~16.4 MB used

    hipLaunchKernelGGL(prep, dim3(4678), dim3(256), 0, stream,
                       states, action, W_edge, b_edge, W_node, b_node, ws16);
    hipLaunchKernelGGL(gnn_main, dim3(640), dim3(512), 0, stream,
                       ws16, (float*)d_out);
}

// Round 8
// 138.251 us; speedup vs baseline: 1.1314x; 1.0232x over previous
//
#include <hip/hip_runtime.h>

typedef _Float16 f16;
typedef _Float16 f16x4 __attribute__((ext_vector_type(4)));
typedef _Float16 f16x8 __attribute__((ext_vector_type(8)));
typedef float    f32x4 __attribute__((ext_vector_type(4)));

#define S2C 2.88539008177792681472f   // 2*log2(e)

// ws layout, f16-element offsets
#define OFF_STF  0u          // states A-frags [10][256 rg2][2 rt][2 ks][64 lane][8]  5242880
#define OFF_AC   5242880u    // action f16 compact [8192][10][16]                     1310720
#define OFF_WEF  6553600u    // W_edge B-frags [90][4 ks][8 cg][64 lane][8]           1474560
#define OFF_WNF  8028160u    // W_node B-frags K-permuted [10][7 ks][4 c][64 lane][8]  143360
#define OFF_BE2  8171520u    // f32: be2[11520], bn2[640]; then 8 f16 zeros
#define OFF_Z    8195840u    // 8 f16 zeros (pad source for action kstep)

__device__ __forceinline__ float fast_exp2(float x){
#if __has_builtin(__builtin_amdgcn_exp2f)
    return __builtin_amdgcn_exp2f(x);
#else
    return exp2f(x);
#endif
}
__device__ __forceinline__ float fast_rcp(float x){
#if __has_builtin(__builtin_amdgcn_rcpf)
    return __builtin_amdgcn_rcpf(x);
#else
    return 1.0f/x;
#endif
}

#define MFMA16(a,b,c) __builtin_amdgcn_mfma_f32_16x16x32_f16(a,b,c,0,0,0)

// ---------------- prologue: cvt + fragment-order + bias scale (unchanged) ----------------
__global__ void prep(const float* __restrict__ st, const float* __restrict__ ac,
                     const float* __restrict__ We, const float* __restrict__ be,
                     const float* __restrict__ Wn, const float* __restrict__ bn,
                     f16* __restrict__ ws16){
    const int bid = blockIdx.x, t = threadIdx.x;
    if (bid < 2560){                                   // states -> A-fragment order
        int g = bid*256 + t;                           // [node][rg2][rt][ks][lane]
        int lane = g&63, ks = (g>>6)&1, rt = (g>>7)&1, rg2 = (g>>8)&255, node = g>>16;
        int row = rg2*32 + rt*16 + (lane&15);
        int k   = ks*32 + (lane>>4)*8;
        const float* src = st + ((size_t)row*10 + node)*64 + k;
        const float4 v0 = *(const float4*)src;
        const float4 v1 = *(const float4*)(src+4);
        f16x8 h; h[0]=(f16)v0.x; h[1]=(f16)v0.y; h[2]=(f16)v0.z; h[3]=(f16)v0.w;
                 h[4]=(f16)v1.x; h[5]=(f16)v1.y; h[6]=(f16)v1.z; h[7]=(f16)v1.w;
        *(f16x8*)(ws16 + OFF_STF + (size_t)g*8) = h;
    } else if (bid < 3840){                            // action f32 -> f16 compact
        int g = (bid-2560)*256 + t;                    // 327680 float4s
        const float4 v = ((const float4*)ac)[g];
        f16x4 h; h[0]=(f16)v.x; h[1]=(f16)v.y; h[2]=(f16)v.z; h[3]=(f16)v.w;
        *(f16x4*)(ws16 + OFF_AC + (size_t)g*4) = h;
    } else if (bid < 4560){                            // W_edge -> B-fragment order
        int g = (bid-3840)*256 + t;                    // < 184320
        int l = g & 15, q = (g>>4)&3, cg = (g>>6)&7, ks = (g>>9)&3, e = g>>11;
        const float* src = We + e*16384 + (ks*32 + q*8)*128 + cg*16 + l;
        f16x8 h;
        #pragma unroll
        for (int u=0;u<8;u++) h[u] = (f16)src[u*128];
        *(f16x8*)(ws16 + OFF_WEF + (size_t)g*8) = h;
    } else if (bid < 4630){                            // W_node -> B-frags, K-permuted
        int g = (bid-4560)*256 + t;                    // < 17920
        if (g < 17920){
            int l = g&15, q=(g>>4)&3, c=(g>>6)&3, r=g>>8;
            int ks2 = r % 7, kn = r / 7;
            f16x8 h;
            #pragma unroll
            for (int u=0;u<8;u++){
                int knew = ks2*32 + q*8 + u;
                // K-order: [agg 0..127 -> f=knew+80][states/action 128..207 -> f=knew-128][pad]
                int f = (knew < 128) ? (knew + 80) : (knew - 128);
                h[u] = (knew < 208) ? (f16)Wn[kn*13312 + f*64 + c*16 + l] : (f16)0.0f;
            }
            *(f16x8*)(ws16 + OFF_WNF + (size_t)kn*14336 + ((size_t)(ks2*4+c)*64 + q*16 + l)*8) = h;
        }
    } else {                                           // biases * 2log2e, zero pad
        int g = (bid-4630)*256 + t;
        float* be2 = (float*)(ws16 + OFF_BE2);
        if (g < 11520)      be2[g] = S2C*be[g];
        else if (g < 12160) be2[g] = S2C*bn[g-11520];
        else if (g < 12168) ws16[OFF_Z + (g-12160)] = (f16)0.0f;
    }
}

// ---------------- main kernel: 128-thread blocks (2 waves, 32 rows), 2560 blocks ----------------
// ILP-first: 256-VGPR budget, fully unrolled edge loop, batched loads before MFMA.
__launch_bounds__(128, 2)
__global__ void gnn_main(const f16* __restrict__ ws16, float* __restrict__ out){
    __shared__ alignas(16) f16 sAgg[32*128];           // 8 KB

    const f16* stf = ws16 + OFF_STF;
    const f16* Wef = ws16 + OFF_WEF;
    const float* be2 = (const float*)(ws16 + OFF_BE2);
    const float* bn2 = be2 + 11520;

    const int t = threadIdx.x, lane = t&63, wid = t>>6;   // wid in {0,1}
    const int l15 = lane&15, q = lane>>4, qo = q<<3;
    const int i  = blockIdx.x >> 8;                    // node 0..9
    const int rb = blockIdx.x & 255;                   // 32-row group 0..255
    const int b0 = rb*32;
    const int cs = wid;                                // H column half

    // states_i A-frags, register-resident across all 9 edges
    f16x8 ai[4];
    {
        const f16* p = stf + (size_t)(i*256 + rb)*2048 + lane*8;
        ai[0] = *(const f16x8*)p;        ai[1] = *(const f16x8*)(p+512);
        ai[2] = *(const f16x8*)(p+1024); ai[3] = *(const f16x8*)(p+1536);
    }

    f32x4 agg[2][4] = {};

    // fully unrolled edge loop: compiler can overlap edge e+1's 20 loads
    // with edge e's ~700-cycle tanh block (needs the 256-VGPR budget).
    #pragma unroll
    for (int e=0; e<9; ++e){
        const int j = e + (e >= i);
        const int ebase = 9*i + e;

        // --- batch 1: aj frags (4 loads) ---
        f16x8 aj[4];
        {
            const f16* p = stf + (size_t)(j*256 + rb)*2048 + lane*8;
            aj[0] = *(const f16x8*)p;        aj[1] = *(const f16x8*)(p+512);
            aj[2] = *(const f16x8*)(p+1024); aj[3] = *(const f16x8*)(p+1536);
        }
        // --- batch 2: all 16 W-fragments for this edge/col-half ---
        f16x8 bf[4][4];
        {
            const f16* wb = Wef + (size_t)((ebase*4)*8 + cs*4)*512 + lane*8;
            #pragma unroll
            for (int ks4=0; ks4<4; ++ks4)
                #pragma unroll
                for (int c=0; c<4; ++c)
                    bf[ks4][c] = *(const f16x8*)(wb + (ks4*8 + c)*512);
        }
        float bv[4];
        #pragma unroll
        for (int c=0; c<4; ++c) bv[c] = be2[ebase*128 + cs*64 + c*16 + l15];

        // --- MFMA: 16 per wave ---
        f32x4 msg[2][4] = {};
        #pragma unroll
        for (int ks4=0; ks4<4; ++ks4){
            #pragma unroll
            for (int rt=0; rt<2; ++rt){
                f16x8 a = (ks4 < 2) ? ai[rt*2 + ks4] : aj[rt*2 + (ks4-2)];
                #pragma unroll
                for (int c=0; c<4; ++c)
                    msg[rt][c] = MFMA16(a, bf[ks4][c], msg[rt][c]);
            }
        }
        // --- tanh + aggregate: sum tanh = 9 - 2*sum rcp(exp2(S2C*x+b2)+1) ---
        #pragma unroll
        for (int rt=0; rt<2; ++rt)
            #pragma unroll
            for (int c=0; c<4; ++c)
                #pragma unroll
                for (int r2=0; r2<4; ++r2){
                    float tt = __builtin_fmaf(msg[rt][c][r2], S2C, bv[c]);
                    float rr = fast_rcp(fast_exp2(tt) + 1.0f);
                    agg[rt][c][r2] = __builtin_fmaf(-2.0f, rr, agg[rt][c][r2]);
                }
    }

    // ---- agg (C-layout) -> sAgg f16 (A-layout, swizzled), +9 fold; ONE barrier ----
    #pragma unroll
    for (int rt=0; rt<2; ++rt)
        #pragma unroll
        for (int c=0; c<4; ++c)
            #pragma unroll
            for (int r2=0; r2<4; ++r2){
                int lrow = rt*16 + q*4 + r2;           // 0..31
                int col  = cs*64 + c*16 + l15;         // 0..127
                sAgg[lrow*128 + (((col>>3) ^ (lrow&7))<<3) + (col&7)] = (f16)(agg[rt][c][r2] + 9.0f);
            }
    __syncthreads();

    // ---- stage 2: out = tanh([agg|states|action] @ Wn_perm[i] + bn) ; wave = 16 rows ----
    f32x4 acc[4] = {};
    const f16* wnb = ws16 + OFF_WNF + (size_t)i*14336;
    const f16* acp = ws16 + OFF_AC;
    const f16* zb  = ws16 + OFF_Z;
    #pragma unroll
    for (int ks2=0; ks2<7; ++ks2){
        f16x8 a;
        if (ks2 < 4){                                  // agg region (K 0..127)
            int lrow = wid*16 + l15;
            a = *(const f16x8*)(sAgg + lrow*128 + (((ks2*4 + q) ^ (l15&7))<<3));
        } else if (ks2 < 6){                           // states region (K 128..191)
            a = *(const f16x8*)(stf + (size_t)(i*256 + rb)*2048 + wid*1024 + (ks2-4)*512 + lane*8);
        } else {                                       // action (K 192..207) + zero pad
            int row = b0 + wid*16 + l15;
            const f16* ap = (q < 2) ? (acp + ((size_t)row*10 + i)*16 + qo) : zb;
            a = *(const f16x8*)ap;
        }
        f16x8 bf[4];
        #pragma unroll
        for (int c=0; c<4; ++c)
            bf[c] = *(const f16x8*)(wnb + (size_t)(ks2*4+c)*512 + lane*8);
        #pragma unroll
        for (int c=0; c<4; ++c)
            acc[c] = MFMA16(a, bf[c], acc[c]);
    }
    float bnv[4];
    #pragma unroll
    for (int c=0; c<4; ++c) bnv[c] = bn2[i*64 + c*16 + l15];
    #pragma unroll
    for (int c=0; c<4; ++c)
        #pragma unroll
        for (int r2=0; r2<4; ++r2){
            int row = b0 + wid*16 + q*4 + r2;
            int col = c*16 + l15;
            float tt = __builtin_fmaf(acc[c][r2], S2C, bnv[c]);
            float rr = fast_rcp(fast_exp2(tt) + 1.0f);
            out[((size_t)row*10 + i)*64 + col] = __builtin_fmaf(-2.0f, rr, 1.0f);
        }
}

extern "C" void kernel_launch(void* const* d_in, const int* in_sizes, int n_in,
                              void* d_out, int out_size, void* d_ws, size_t ws_size,
                              hipStream_t stream) {
    const float* states = (const float*)d_in[0];
    const float* action = (const float*)d_in[1];
    const float* W_edge = (const float*)d_in[2];
    const float* b_edge = (const float*)d_in[3];
    const float* W_node = (const float*)d_in[4];
    const float* b_node = (const float*)d_in[5];
    f16* ws16 = (f16*)d_ws;   // ~16.4 MB used

    hipLaunchKernelGGL(prep, dim3(4678), dim3(256), 0, stream,
                       states, action, W_edge, b_edge, W_node, b_node, ws16);
    hipLaunchKernelGGL(gnn_main, dim3(2560), dim3(128), 0, stream,
                       ws16, (float*)d_out);
}

// Round 9
// 136.548 us; speedup vs baseline: 1.1455x; 1.0125x over previous
//
#include <hip/hip_runtime.h>

typedef _Float16 f16;
typedef _Float16 f16x4 __attribute__((ext_vector_type(4)));
typedef _Float16 f16x8 __attribute__((ext_vector_type(8)));
typedef float    f32x4 __attribute__((ext_vector_type(4)));

#define S2C 2.88539008177792681472f   // 2*log2(e)

// ws layout, f16-element offsets
#define OFF_STF  0u          // states A-frags [10][256 rg2][2 rt][2 ks][64 lane][8]  5242880
#define OFF_AC   5242880u    // action f16 compact [8192][10][16]                     1310720
#define OFF_WEF  6553600u    // W_edge B-frags [90][4 ks][8 cg][64 lane][8]           1474560
#define OFF_WNF  8028160u    // W_node B-frags K-permuted [10][7 ks][4 c][64 lane][8]  143360
#define OFF_BE2  8171520u    // f32: be2[11520], bn2[640]; then 8 f16 zeros
#define OFF_Z    8195840u    // 8 f16 zeros (pad source for action kstep)

__device__ __forceinline__ float fast_exp2(float x){
#if __has_builtin(__builtin_amdgcn_exp2f)
    return __builtin_amdgcn_exp2f(x);
#else
    return exp2f(x);
#endif
}
__device__ __forceinline__ float fast_rcp(float x){
#if __has_builtin(__builtin_amdgcn_rcpf)
    return __builtin_amdgcn_rcpf(x);
#else
    return 1.0f/x;
#endif
}

#define MFMA16(a,b,c) __builtin_amdgcn_mfma_f32_16x16x32_f16(a,b,c,0,0,0)

// ---------------- prologue: cvt + fragment-order + bias scale (unchanged) ----------------
__global__ void prep(const float* __restrict__ st, const float* __restrict__ ac,
                     const float* __restrict__ We, const float* __restrict__ be,
                     const float* __restrict__ Wn, const float* __restrict__ bn,
                     f16* __restrict__ ws16){
    const int bid = blockIdx.x, t = threadIdx.x;
    if (bid < 2560){                                   // states -> A-fragment order
        int g = bid*256 + t;                           // [node][rg2][rt][ks][lane]
        int lane = g&63, ks = (g>>6)&1, rt = (g>>7)&1, rg2 = (g>>8)&255, node = g>>16;
        int row = rg2*32 + rt*16 + (lane&15);
        int k   = ks*32 + (lane>>4)*8;
        const float* src = st + ((size_t)row*10 + node)*64 + k;
        const float4 v0 = *(const float4*)src;
        const float4 v1 = *(const float4*)(src+4);
        f16x8 h; h[0]=(f16)v0.x; h[1]=(f16)v0.y; h[2]=(f16)v0.z; h[3]=(f16)v0.w;
                 h[4]=(f16)v1.x; h[5]=(f16)v1.y; h[6]=(f16)v1.z; h[7]=(f16)v1.w;
        *(f16x8*)(ws16 + OFF_STF + (size_t)g*8) = h;
    } else if (bid < 3840){                            // action f32 -> f16 compact
        int g = (bid-2560)*256 + t;                    // 327680 float4s
        const float4 v = ((const float4*)ac)[g];
        f16x4 h; h[0]=(f16)v.x; h[1]=(f16)v.y; h[2]=(f16)v.z; h[3]=(f16)v.w;
        *(f16x4*)(ws16 + OFF_AC + (size_t)g*4) = h;
    } else if (bid < 4560){                            // W_edge -> B-fragment order
        int g = (bid-3840)*256 + t;                    // < 184320
        int l = g & 15, q = (g>>4)&3, cg = (g>>6)&7, ks = (g>>9)&3, e = g>>11;
        const float* src = We + e*16384 + (ks*32 + q*8)*128 + cg*16 + l;
        f16x8 h;
        #pragma unroll
        for (int u=0;u<8;u++) h[u] = (f16)src[u*128];
        *(f16x8*)(ws16 + OFF_WEF + (size_t)g*8) = h;
    } else if (bid < 4630){                            // W_node -> B-frags, K-permuted
        int g = (bid-4560)*256 + t;                    // < 17920
        if (g < 17920){
            int l = g&15, q=(g>>4)&3, c=(g>>6)&3, r=g>>8;
            int ks2 = r % 7, kn = r / 7;
            f16x8 h;
            #pragma unroll
            for (int u=0;u<8;u++){
                int knew = ks2*32 + q*8 + u;
                // K-order: [agg 0..127 -> f=knew+80][states/action 128..207 -> f=knew-128][pad]
                int f = (knew < 128) ? (knew + 80) : (knew - 128);
                h[u] = (knew < 208) ? (f16)Wn[kn*13312 + f*64 + c*16 + l] : (f16)0.0f;
            }
            *(f16x8*)(ws16 + OFF_WNF + (size_t)kn*14336 + ((size_t)(ks2*4+c)*64 + q*16 + l)*8) = h;
        }
    } else {                                           // biases * 2log2e, zero pad
        int g = (bid-4630)*256 + t;
        float* be2 = (float*)(ws16 + OFF_BE2);
        if (g < 11520)      be2[g] = S2C*be[g];
        else if (g < 12160) be2[g] = S2C*bn[g-11520];
        else if (g < 12168) ws16[OFF_Z + (g-12160)] = (f16)0.0f;
    }
}

// ---------------- main kernel: explicit register double-buffer pipeline ----------------
// 128-thread blocks (2 waves, 32 rows), 2560 blocks. Next edge's 20 fragments are
// loaded into the alternate register buffer at the TOP of each edge body; their
// waitcnt lands at the NEXT edge's MFMA, hidden behind this edge's MFMA+tanh.
__launch_bounds__(128, 2)
__global__ void gnn_main(const f16* __restrict__ ws16, float* __restrict__ out){
    __shared__ alignas(16) f16 sAgg[32*128];           // 8 KB

    const f16* stf = ws16 + OFF_STF;
    const f16* Wef = ws16 + OFF_WEF;
    const float* be2 = (const float*)(ws16 + OFF_BE2);
    const float* bn2 = be2 + 11520;

    const int t = threadIdx.x, lane = t&63, wid = t>>6;   // wid in {0,1}
    const int l15 = lane&15, q = lane>>4, qo = q<<3;
    const int i  = blockIdx.x >> 8;                    // node 0..9
    const int rb = blockIdx.x & 255;                   // 32-row group 0..255
    const int b0 = rb*32;
    const int cs = wid;                                // H column half
    const int e0 = 9*i;

    // double-buffered operand registers
    f16x8 ajb[2][4];
    f16x8 bfb[2][4][4];

    // prologue: issue edge-0 loads first, then ai (independent, also in flight)
    {
        const int j0 = (i==0) ? 1 : 0;
        const f16* p = stf + (size_t)(j0*256 + rb)*2048 + lane*8;
        #pragma unroll
        for (int r=0; r<4; ++r) ajb[0][r] = *(const f16x8*)(p + r*512);
        const f16* wb = Wef + (size_t)(e0*32 + cs*4)*512 + lane*8;
        #pragma unroll
        for (int ks4=0; ks4<4; ++ks4)
            #pragma unroll
            for (int c=0; c<4; ++c)
                bfb[0][ks4][c] = *(const f16x8*)(wb + (ks4*8 + c)*512);
    }
    f16x8 ai[4];
    {
        const f16* p = stf + (size_t)(i*256 + rb)*2048 + lane*8;
        ai[0] = *(const f16x8*)p;        ai[1] = *(const f16x8*)(p+512);
        ai[2] = *(const f16x8*)(p+1024); ai[3] = *(const f16x8*)(p+1536);
    }

    f32x4 agg[2][4] = {};

    #pragma unroll
    for (int e=0; e<9; ++e){
        const int cur = e&1, nxt = cur^1;
        const int ebase = e0 + e;

        // ---- prefetch edge e+1 into the alternate buffer (no consumer here) ----
        if (e < 8){
            const int j2 = (e+1) + ((e+1) >= i);
            const f16* p = stf + (size_t)(j2*256 + rb)*2048 + lane*8;
            #pragma unroll
            for (int r=0; r<4; ++r) ajb[nxt][r] = *(const f16x8*)(p + r*512);
            const f16* wb = Wef + (size_t)((ebase+1)*32 + cs*4)*512 + lane*8;
            #pragma unroll
            for (int ks4=0; ks4<4; ++ks4)
                #pragma unroll
                for (int c=0; c<4; ++c)
                    bfb[nxt][ks4][c] = *(const f16x8*)(wb + (ks4*8 + c)*512);
        }
        float bv[4];
        #pragma unroll
        for (int c=0; c<4; ++c) bv[c] = be2[ebase*128 + cs*64 + c*16 + l15];

        // ---- compute on the CURRENT buffer, one row-tile at a time (msg = 16 VGPR) ----
        #pragma unroll
        for (int rt=0; rt<2; ++rt){
            f32x4 msg[4] = {};
            #pragma unroll
            for (int ks4=0; ks4<4; ++ks4){
                f16x8 a = (ks4 < 2) ? ai[rt*2 + ks4] : ajb[cur][rt*2 + (ks4-2)];
                #pragma unroll
                for (int c=0; c<4; ++c)
                    msg[c] = MFMA16(a, bfb[cur][ks4][c], msg[c]);
            }
            // tanh + aggregate: sum tanh = 9 - 2*sum rcp(exp2(S2C*x+b2)+1)
            #pragma unroll
            for (int c=0; c<4; ++c)
                #pragma unroll
                for (int r2=0; r2<4; ++r2){
                    float tt = __builtin_fmaf(msg[c][r2], S2C, bv[c]);
                    float rr = fast_rcp(fast_exp2(tt) + 1.0f);
                    agg[rt][c][r2] = __builtin_fmaf(-2.0f, rr, agg[rt][c][r2]);
                }
        }
    }

    // ---- agg (C-layout) -> sAgg f16 (A-layout, swizzled), +9 fold; ONE barrier ----
    #pragma unroll
    for (int rt=0; rt<2; ++rt)
        #pragma unroll
        for (int c=0; c<4; ++c)
            #pragma unroll
            for (int r2=0; r2<4; ++r2){
                int lrow = rt*16 + q*4 + r2;           // 0..31
                int col  = cs*64 + c*16 + l15;         // 0..127
                sAgg[lrow*128 + (((col>>3) ^ (lrow&7))<<3) + (col&7)] = (f16)(agg[rt][c][r2] + 9.0f);
            }
    __syncthreads();

    // ---- stage 2: out = tanh([agg|states|action] @ Wn_perm[i] + bn) ; wave = 16 rows ----
    f32x4 acc[4] = {};
    const f16* wnb = ws16 + OFF_WNF + (size_t)i*14336;
    const f16* acp = ws16 + OFF_AC;
    const f16* zb  = ws16 + OFF_Z;
    #pragma unroll
    for (int ks2=0; ks2<7; ++ks2){
        f16x8 a;
        if (ks2 < 4){                                  // agg region (K 0..127)
            int lrow = wid*16 + l15;
            a = *(const f16x8*)(sAgg + lrow*128 + (((ks2*4 + q) ^ (l15&7))<<3));
        } else if (ks2 < 6){                           // states region (K 128..191)
            a = *(const f16x8*)(stf + (size_t)(i*256 + rb)*2048 + wid*1024 + (ks2-4)*512 + lane*8);
        } else {                                       // action (K 192..207) + zero pad
            int row = b0 + wid*16 + l15;
            const f16* ap = (q < 2) ? (acp + ((size_t)row*10 + i)*16 + qo) : zb;
            a = *(const f16x8*)ap;
        }
        f16x8 bf[4];
        #pragma unroll
        for (int c=0; c<4; ++c)
            bf[c] = *(const f16x8*)(wnb + (size_t)(ks2*4+c)*512 + lane*8);
        #pragma unroll
        for (int c=0; c<4; ++c)
            acc[c] = MFMA16(a, bf[c], acc[c]);
    }
    float bnv[4];
    #pragma unroll
    for (int c=0; c<4; ++c) bnv[c] = bn2[i*64 + c*16 + l15];
    #pragma unroll
    for (int c=0; c<4; ++c)
        #pragma unroll
        for (int r2=0; r2<4; ++r2){
            int row = b0 + wid*16 + q*4 + r2;
            int col = c*16 + l15;
            float tt = __builtin_fmaf(acc[c][r2], S2C, bnv[c]);
            float rr = fast_rcp(fast_exp2(tt) + 1.0f);
            out[((size_t)row*10 + i)*64 + col] = __builtin_fmaf(-2.0f, rr, 1.0f);
        }
}

extern "C" void kernel_launch(void* const* d_in, const int* in_sizes, int n_in,
                              void* d_out, int out_size, void* d_ws, size_t ws_size,
                              hipStream_t stream) {
    const float* states = (const float*)d_in[0];
    const float* action = (const float*)d_in[1];
    const float* W_edge = (const float*)d_in[2];
    const float* b_edge = (const float*)d_in[3];
    const float* W_node = (const float*)d_in[4];
    const float* b_node = (const float*)d_in[5];
    f16* ws16 = (f16*)d_ws;   // ~16.4 MB used

    hipLaunchKernelGGL(prep, dim3(4678), dim3(256), 0, stream,
                       states, action, W_edge, b_edge, W_node, b_node, ws16);
    hipLaunchKernelGGL(gnn_main, dim3(2560), dim3(128), 0, stream,
                       ws16, (float*)d_out);
}